// Round 1
// baseline (16408.154 us; speedup 1.0000x reference)
//
#include <hip/hip_runtime.h>

// LSTM forward, persistent-kernel design:
//   B=64, S=512, D=256, H=1024.  gates = [x_t | H_{t-1}] (64x1280) @ Wpack (1280x4096) + b
//   128 blocks x 256 threads; block j owns h in [8j, 8j+8) -> 32 gate columns (i,f,o,c x8).
//   - B-slice (1280x32 bf16 = 80KB) pre-swizzled to MFMA B-frag order, resident in LDS.
//   - A staged per step in double-buffered LDS chunks of K=256 (rows padded to 264).
//   - 16x16x32 bf16 MFMA, 4-way K-split across waves, LDS reduction (aliases A bufs).
//   - C-state in registers; H exchanged via double-buffered global bf16 buffer;
//     one device-scope atomic barrier per step (monotonic counter in ws).
//   - pred[b,t] = bd + sum_h H*Wd accumulated with atomicAdd (init'd by prep kernel).

#define NB   128
#define SEQ  512
#define BATCH 64
#define DIM  256
#define HU   1024

typedef unsigned short u16;
typedef unsigned int   u32;
typedef __attribute__((ext_vector_type(8))) short  short8;
typedef __attribute__((ext_vector_type(4))) float  f32x4;

__device__ __forceinline__ u16 f2bf(float x) {
  u32 u = __float_as_uint(x);
  u32 r = (u + 0x7FFFu + ((u >> 16) & 1u)) >> 16;   // RNE
  return (u16)r;
}
__device__ __forceinline__ float sigf(float x)  { return 1.0f / (1.0f + __expf(-x)); }
__device__ __forceinline__ float tanhfast(float x) { return 1.0f - 2.0f / (1.0f + __expf(2.0f * x)); }

// ---------------- prologue kernels ----------------

// 65536 threads: zero barrier, pred = bd, Hbuf[0] = bf16(H0)
__global__ void k_prep(const float* __restrict__ H0, const float* __restrict__ bd,
                       u16* __restrict__ Hbuf0, float* __restrict__ pred, u32* __restrict__ bar) {
  int i = blockIdx.x * 256 + threadIdx.x;
  if (i == 0) *bar = 0u;
  if (i < BATCH * SEQ) pred[i] = bd[0];
  Hbuf0[i] = f2bf(H0[i]);   // i < 65536 == BATCH*HU
}

// inputs fp32 (B,S,D) -> bf16 same layout; 2097152 threads, 4 elems each
__global__ void k_xconv(const float* __restrict__ in, u16* __restrict__ out) {
  int i = blockIdx.x * 256 + threadIdx.x;
  float4 v = ((const float4*)in)[i];
  ushort4 o;
  o.x = f2bf(v.x); o.y = f2bf(v.y); o.z = f2bf(v.z); o.w = f2bf(v.w);
  ((ushort4*)out)[i] = o;
}

// Build Wpack[j][nt(2)][kc(40)][lane(64)][8] bf16 : exact MFMA B-fragment order.
// element (lane,e): n = nt*16 + (lane&15) (local col), k = kc*32 + (lane>>4)*8 + e
// local col -> gate = col>>3 (i,f,o,c), h = j*8 + (col&7); k<256 -> Wx[gate], else Wh[gate].
__global__ void k_pack(const float* __restrict__ Wxi, const float* __restrict__ Whi,
                       const float* __restrict__ Wxf, const float* __restrict__ Whf,
                       const float* __restrict__ Wxo, const float* __restrict__ Who,
                       const float* __restrict__ Wxc, const float* __restrict__ Whc,
                       u16* __restrict__ Wpack) {
  int tid  = blockIdx.x * 256 + threadIdx.x;   // < 128*2*40*64 = 655360
  int lane = tid & 63;
  int kc   = (tid >> 6) % 40;
  int nt   = ((tid >> 6) / 40) & 1;
  int j    = (tid >> 6) / 80;
  int col  = nt * 16 + (lane & 15);
  int gate = col >> 3;
  int h    = j * 8 + (col & 7);
  const float* Wx = (gate == 0) ? Wxi : (gate == 1) ? Wxf : (gate == 2) ? Wxo : Wxc;
  const float* Wh = (gate == 0) ? Whi : (gate == 1) ? Whf : (gate == 2) ? Who : Whc;
  int kbase = kc * 32 + ((lane >> 4) << 3);
  u16 tmp[8];
#pragma unroll
  for (int e = 0; e < 8; e++) {
    int k = kbase + e;
    float v = (k < DIM) ? Wx[k * HU + h] : Wh[(k - DIM) * HU + h];
    tmp[e] = f2bf(v);
  }
  *(uint4*)(Wpack + (size_t)tid * 8) = *(uint4*)tmp;
}

// ---------------- main persistent kernel ----------------

struct MainParams {
  const u16* __restrict__ xbf;     // (B,S,D) bf16
  const u16* __restrict__ Wpack;   // [NB][2][40][64][8] bf16
  u16* __restrict__ Hbuf;          // [2][B][HU] bf16 (double buffer)
  const float* __restrict__ C0;
  const float* __restrict__ Wd;
  const float* __restrict__ bi;
  const float* __restrict__ bfg;
  const float* __restrict__ bo;
  const float* __restrict__ bc;
  float* __restrict__ pred;        // [B][SEQ]
  float* __restrict__ Hf;          // [B][HU]
  float* __restrict__ Cf;          // [B][HU]
  u32* __restrict__ bar;
};

__global__ __launch_bounds__(256, 1) void lstm_main(MainParams p) {
  __shared__ u16 Bsm[2 * 40 * 64 * 8];     // 81920 B, B-fragments, resident all steps
  __shared__ u16 Abuf[2][64 * 264];        // 2 x 33792 B, A staging (rows padded 256->264)
  float* red = (float*)&Abuf[0][0];        // 34816 B reduction scratch, aliases A bufs

  const int tid  = threadIdx.x;
  const int wave = tid >> 6, lane = tid & 63;
  const int j    = blockIdx.x;

  // load resident B slice (80KB) once
  {
    const uint4* src = (const uint4*)(p.Wpack + (size_t)j * 40960);
    uint4* dst = (uint4*)Bsm;
#pragma unroll
    for (int i = 0; i < 20; i++) dst[tid + i * 256] = src[tid + i * 256];
  }

  // per-thread state: (b_, 2 h's)
  const int b_  = tid >> 2, hq = tid & 3;
  const int hg0 = j * 8 + hq * 2, hg1 = hg0 + 1;
  float c0v = p.C0[b_ * HU + hg0], c1v = p.C0[b_ * HU + hg1];
  const float wd0 = p.Wd[hg0], wd1 = p.Wd[hg1];
  const float bi0 = p.bi[hg0],  bi1 = p.bi[hg1];
  const float bf0 = p.bfg[hg0], bf1 = p.bfg[hg1];
  const float bo0 = p.bo[hg0],  bo1 = p.bo[hg1];
  const float bc0 = p.bc[hg0],  bc1 = p.bc[hg1];
  float h0f = 0.f, h1f = 0.f;

  __syncthreads();

#pragma unroll 1
  for (int t = 0; t < SEQ; t++) {
    const int rb = t & 1;
    const u16* Hr = p.Hbuf + (size_t)rb * (BATCH * HU);
    u16*       Hw = p.Hbuf + (size_t)(rb ^ 1) * (BATCH * HU);

    // stage chunk 0 (x_t) into Abuf[0]
#pragma unroll
    for (int i = 0; i < 8; i++) {
      int g = tid + i * 256, row = g >> 5, c8 = g & 31;
      uint4 v = *(const uint4*)(p.xbf + ((size_t)(row * SEQ + t)) * DIM + c8 * 8);
      *(uint4*)(&Abuf[0][row * 264 + c8 * 8]) = v;
    }

    f32x4 acc[4][2];
#pragma unroll
    for (int mt = 0; mt < 4; mt++)
#pragma unroll
      for (int nt = 0; nt < 2; nt++) acc[mt][nt] = (f32x4){0.f, 0.f, 0.f, 0.f};

    __syncthreads();

    // 5 staged K-chunks of 256 (chunk0 = x, 1..4 = H), double-buffered
#pragma unroll
    for (int c = 0; c < 5; c++) {
      uint4 pf[8];
      if (c < 4) {
#pragma unroll
        for (int i = 0; i < 8; i++) {
          int g = tid + i * 256, row = g >> 5, c8 = g & 31;
          pf[i] = *(const uint4*)(Hr + row * HU + c * DIM + c8 * 8);
        }
      }
      const u16* A = &Abuf[c & 1][0];
      // 4-way K-split: wave handles sub-chunks {wave, wave+4} of 8x K=32
#pragma unroll
      for (int si = 0; si < 2; si++) {
        const int s   = wave + si * 4;
        const int kcg = c * 8 + s;                       // global k-chunk 0..39
        const int kl  = s * 32 + ((lane >> 4) << 3);     // elem offset in staged chunk
        short8 bfr0 = *(const short8*)(Bsm + (0 * 40 + kcg) * 512 + lane * 8);
        short8 bfr1 = *(const short8*)(Bsm + (1 * 40 + kcg) * 512 + lane * 8);
#pragma unroll
        for (int mt = 0; mt < 4; mt++) {
          short8 af = *(const short8*)(A + (mt * 16 + (lane & 15)) * 264 + kl);
          acc[mt][0] = __builtin_amdgcn_mfma_f32_16x16x32_bf16(af, bfr0, acc[mt][0], 0, 0, 0);
          acc[mt][1] = __builtin_amdgcn_mfma_f32_16x16x32_bf16(af, bfr1, acc[mt][1], 0, 0, 0);
        }
      }
      if (c < 4) {
#pragma unroll
        for (int i = 0; i < 8; i++) {
          int g = tid + i * 256, row = g >> 5, c8 = g & 31;
          *(uint4*)(&Abuf[(c + 1) & 1][row * 264 + c8 * 8]) = pf[i];
        }
      }
      __syncthreads();
    }

    // K-split reduction: red[wave][col(32)][68 rows-padded], col-major so 4 regs = float4
    {
      const int cb = lane & 15, q = lane >> 4;
#pragma unroll
      for (int mt = 0; mt < 4; mt++)
#pragma unroll
        for (int nt = 0; nt < 2; nt++) {
          int addr = (wave * 32 + nt * 16 + cb) * 68 + mt * 16 + q * 4;
          *(f32x4*)(red + addr) = acc[mt][nt];
        }
    }
    __syncthreads();

    // epilogue: thread owns (b_, hg0, hg1)
    float gv[8];
#pragma unroll
    for (int gg = 0; gg < 4; gg++)
#pragma unroll
      for (int e = 0; e < 2; e++) {
        int col = gg * 8 + hq * 2 + e;
        gv[gg * 2 + e] = red[(0 * 32 + col) * 68 + b_] + red[(1 * 32 + col) * 68 + b_]
                       + red[(2 * 32 + col) * 68 + b_] + red[(3 * 32 + col) * 68 + b_];
      }
    float i0 = sigf(gv[0] + bi0), i1 = sigf(gv[1] + bi1);
    float f0 = sigf(gv[2] + bf0), f1 = sigf(gv[3] + bf1);
    float o0 = sigf(gv[4] + bo0), o1 = sigf(gv[5] + bo1);
    float ct0 = tanhfast(gv[6] + bc0), ct1 = tanhfast(gv[7] + bc1);
    c0v = f0 * c0v + i0 * ct0;  c1v = f1 * c1v + i1 * ct1;
    h0f = o0 * tanhfast(c0v);   h1f = o1 * tanhfast(c1v);

    // pred partial: reduce 4 threads sharing b_, one atomic per group
    float pr = h0f * wd0 + h1f * wd1;
    pr += __shfl_xor(pr, 1);
    pr += __shfl_xor(pr, 2);
    if ((lane & 3) == 0) atomicAdd(p.pred + b_ * SEQ + t, pr);

    // publish H_t (bf16 pair as one dword)
    u32 hv = (u32)f2bf(h0f) | ((u32)f2bf(h1f) << 16);
    *(u32*)(Hw + b_ * HU + hg0) = hv;

    // grid barrier (monotonic counter)
    __threadfence();
    __syncthreads();
    if (tid == 0) {
      __hip_atomic_fetch_add(p.bar, 1u, __ATOMIC_RELEASE, __HIP_MEMORY_SCOPE_AGENT);
      const u32 tgt = (u32)(NB * (t + 1));
      while (__hip_atomic_load(p.bar, __ATOMIC_RELAXED, __HIP_MEMORY_SCOPE_AGENT) < tgt)
        __builtin_amdgcn_s_sleep(1);
    }
    __syncthreads();
    __threadfence();
  }

  // finals
  p.Hf[b_ * HU + hg0] = h0f; p.Hf[b_ * HU + hg1] = h1f;
  p.Cf[b_ * HU + hg0] = c0v; p.Cf[b_ * HU + hg1] = c1v;
}

// ---------------- launch ----------------

extern "C" void kernel_launch(void* const* d_in, const int* in_sizes, int n_in,
                              void* d_out, int out_size, void* d_ws, size_t ws_size,
                              hipStream_t stream) {
  const float* inputs = (const float*)d_in[0];
  const float* H0  = (const float*)d_in[1];
  const float* C0  = (const float*)d_in[2];
  const float* Wxi = (const float*)d_in[3];
  const float* Whi = (const float*)d_in[4];
  const float* bi  = (const float*)d_in[5];
  const float* Wxf = (const float*)d_in[6];
  const float* Whf = (const float*)d_in[7];
  const float* bf_ = (const float*)d_in[8];
  const float* Wxo = (const float*)d_in[9];
  const float* Who = (const float*)d_in[10];
  const float* bo  = (const float*)d_in[11];
  const float* Wxc = (const float*)d_in[12];
  const float* Whc = (const float*)d_in[13];
  const float* bc  = (const float*)d_in[14];
  const float* Wd  = (const float*)d_in[15];
  const float* bd  = (const float*)d_in[16];

  char* ws = (char*)d_ws;
  u32* bar   = (u32*)ws;                                     // 128 B
  u16* Wpack = (u16*)(ws + 128);                             // 10485760 B
  u16* xbf   = (u16*)(ws + 128 + 10485760);                  // 16777216 B
  u16* Hbuf  = (u16*)(ws + 128 + 10485760 + 16777216);       // 262144 B  (total ~27.5 MB)

  float* pred = (float*)d_out;
  float* Hf   = pred + BATCH * SEQ;
  float* Cf   = Hf + BATCH * HU;

  k_prep<<<256, 256, 0, stream>>>(H0, bd, Hbuf, pred, bar);
  k_xconv<<<8192, 256, 0, stream>>>(inputs, xbf);
  k_pack<<<2560, 256, 0, stream>>>(Wxi, Whi, Wxf, Whf, Wxo, Who, Wxc, Whc, Wpack);

  MainParams prm{xbf, Wpack, Hbuf, C0, Wd, bi, bf_, bo, bc, pred, Hf, Cf, bar};
  lstm_main<<<dim3(NB), dim3(256), 0, stream>>>(prm);
}

// Round 2
// 3569.610 us; speedup vs baseline: 4.5966x; 4.5966x over previous
//
#include <hip/hip_runtime.h>

// LSTM forward, persistent-kernel, R2:
//   R1 post-mortem: __threadfence() at agent scope = whole-L2 wbl2/inv per step
//   (gfx950 per-XCD L2 non-coherent) -> 32 us/step, 99% idle. R2 removes ALL
//   fences from the step loop:
//   - H exchange via relaxed agent-scope atomics (sc1: per-access LLC coherence).
//   - Barrier: relaxed monotonic counter; ordering via the vmcnt(0) drain that
//     __syncthreads already performs before tid0's arrival add.
//   - pred: per-block partials to ws with plain stores; trailing k_predsum kernel.

#define NB   128
#define SEQ  512
#define BATCH 64
#define DIM  256
#define HU   1024

typedef unsigned short u16;
typedef unsigned int   u32;
typedef unsigned long long u64;
typedef __attribute__((ext_vector_type(8))) short  short8;
typedef __attribute__((ext_vector_type(4))) float  f32x4;

__device__ __forceinline__ u16 f2bf(float x) {
  u32 u = __float_as_uint(x);
  u32 r = (u + 0x7FFFu + ((u >> 16) & 1u)) >> 16;   // RNE
  return (u16)r;
}
__device__ __forceinline__ float sigf(float x)  { return 1.0f / (1.0f + __expf(-x)); }
__device__ __forceinline__ float tanhfast(float x) { return 1.0f - 2.0f / (1.0f + __expf(2.0f * x)); }

// ---------------- prologue kernels ----------------

// 65536 threads: zero barrier, Hbuf[0] = bf16(H0)
__global__ void k_prep(const float* __restrict__ H0, u16* __restrict__ Hbuf0,
                       u32* __restrict__ bar) {
  int i = blockIdx.x * 256 + threadIdx.x;
  if (i == 0) *bar = 0u;
  Hbuf0[i] = f2bf(H0[i]);   // i < 65536 == BATCH*HU
}

// inputs fp32 (B,S,D) -> bf16 same layout; 2097152 threads, 4 elems each
__global__ void k_xconv(const float* __restrict__ in, u16* __restrict__ out) {
  int i = blockIdx.x * 256 + threadIdx.x;
  float4 v = ((const float4*)in)[i];
  ushort4 o;
  o.x = f2bf(v.x); o.y = f2bf(v.y); o.z = f2bf(v.z); o.w = f2bf(v.w);
  ((ushort4*)out)[i] = o;
}

// Build Wpack[j][nt(2)][kc(40)][lane(64)][8] bf16 : exact MFMA B-fragment order.
__global__ void k_pack(const float* __restrict__ Wxi, const float* __restrict__ Whi,
                       const float* __restrict__ Wxf, const float* __restrict__ Whf,
                       const float* __restrict__ Wxo, const float* __restrict__ Who,
                       const float* __restrict__ Wxc, const float* __restrict__ Whc,
                       u16* __restrict__ Wpack) {
  int tid  = blockIdx.x * 256 + threadIdx.x;   // < 128*2*40*64 = 655360
  int lane = tid & 63;
  int kc   = (tid >> 6) % 40;
  int nt   = ((tid >> 6) / 40) & 1;
  int j    = (tid >> 6) / 80;
  int col  = nt * 16 + (lane & 15);
  int gate = col >> 3;
  int h    = j * 8 + (col & 7);
  const float* Wx = (gate == 0) ? Wxi : (gate == 1) ? Wxf : (gate == 2) ? Wxo : Wxc;
  const float* Wh = (gate == 0) ? Whi : (gate == 1) ? Whf : (gate == 2) ? Who : Whc;
  int kbase = kc * 32 + ((lane >> 4) << 3);
  u16 tmp[8];
#pragma unroll
  for (int e = 0; e < 8; e++) {
    int k = kbase + e;
    float v = (k < DIM) ? Wx[k * HU + h] : Wh[(k - DIM) * HU + h];
    tmp[e] = f2bf(v);
  }
  *(uint4*)(Wpack + (size_t)tid * 8) = *(uint4*)tmp;
}

// pred[b,t] = bd + sum_j part[t][j][b];  32768 threads
__global__ void k_predsum(const float* __restrict__ part, const float* __restrict__ bd,
                          float* __restrict__ pred) {
  int i = blockIdx.x * 256 + threadIdx.x;
  int b = i & 63, t = i >> 6;
  float s = bd[0];
  const float* p0 = part + (size_t)t * NB * 64 + b;
#pragma unroll 8
  for (int jj = 0; jj < NB; jj++) s += p0[jj * 64];
  pred[b * SEQ + t] = s;
}

// ---------------- main persistent kernel ----------------

struct MainParams {
  const u16* __restrict__ xbf;     // (B,S,D) bf16
  const u16* __restrict__ Wpack;   // [NB][2][40][64][8] bf16
  u16* __restrict__ Hbuf;          // [2][B][HU] bf16 (double buffer)
  const float* __restrict__ C0;
  const float* __restrict__ Wd;
  const float* __restrict__ bi;
  const float* __restrict__ bfg;
  const float* __restrict__ bo;
  const float* __restrict__ bc;
  float* __restrict__ ppart;       // [SEQ][NB][64] pred partials
  float* __restrict__ Hf;          // [B][HU]
  float* __restrict__ Cf;          // [B][HU]
  u32* __restrict__ bar;
};

__global__ __launch_bounds__(256, 1) void lstm_main(MainParams p) {
  __shared__ u16 Bsm[2 * 40 * 64 * 8];     // 81920 B, B-fragments, resident all steps
  __shared__ u16 Abuf[2][64 * 264];        // 2 x 33792 B, A staging (rows padded 256->264)
  float* red = (float*)&Abuf[0][0];        // 34816 B reduction scratch, aliases A bufs

  const int tid  = threadIdx.x;
  const int wave = tid >> 6, lane = tid & 63;
  const int j    = blockIdx.x;

  // load resident B slice (80KB) once
  {
    const uint4* src = (const uint4*)(p.Wpack + (size_t)j * 40960);
    uint4* dst = (uint4*)Bsm;
#pragma unroll
    for (int i = 0; i < 20; i++) dst[tid + i * 256] = src[tid + i * 256];
  }

  // per-thread state: (b_, 2 h's)
  const int b_  = tid >> 2, hq = tid & 3;
  const int hg0 = j * 8 + hq * 2, hg1 = hg0 + 1;
  float c0v = p.C0[b_ * HU + hg0], c1v = p.C0[b_ * HU + hg1];
  const float wd0 = p.Wd[hg0], wd1 = p.Wd[hg1];
  const float bi0 = p.bi[hg0],  bi1 = p.bi[hg1];
  const float bf0 = p.bfg[hg0], bf1 = p.bfg[hg1];
  const float bo0 = p.bo[hg0],  bo1 = p.bo[hg1];
  const float bc0 = p.bc[hg0],  bc1 = p.bc[hg1];
  float h0f = 0.f, h1f = 0.f;

  __syncthreads();

#pragma unroll 1
  for (int t = 0; t < SEQ; t++) {
    const int rb = t & 1;
    const u16* Hr = p.Hbuf + (size_t)rb * (BATCH * HU);
    u16*       Hw = p.Hbuf + (size_t)(rb ^ 1) * (BATCH * HU);

    // stage chunk 0 (x_t) into Abuf[0] (read-only input: plain cached loads)
#pragma unroll
    for (int i = 0; i < 8; i++) {
      int g = tid + i * 256, row = g >> 5, c8 = g & 31;
      uint4 v = *(const uint4*)(p.xbf + ((size_t)(row * SEQ + t)) * DIM + c8 * 8);
      *(uint4*)(&Abuf[0][row * 264 + c8 * 8]) = v;
    }

    f32x4 acc[4][2];
#pragma unroll
    for (int mt = 0; mt < 4; mt++)
#pragma unroll
      for (int nt = 0; nt < 2; nt++) acc[mt][nt] = (f32x4){0.f, 0.f, 0.f, 0.f};

    __syncthreads();

    // 5 staged K-chunks of 256 (chunk0 = x, 1..4 = H), double-buffered.
    // H loads are relaxed agent-scope atomics -> global_load sc1 (LLC-coherent,
    // no stale per-XCD L2 lines, no fences needed).
#pragma unroll
    for (int c = 0; c < 5; c++) {
      u64 pf[16];
      if (c < 4) {
#pragma unroll
        for (int i = 0; i < 8; i++) {
          int g = tid + i * 256, row = g >> 5, c8 = g & 31;
          const u64* s8 = (const u64*)(Hr + row * HU + c * DIM + c8 * 8);
          pf[2 * i]     = __hip_atomic_load(s8,     __ATOMIC_RELAXED, __HIP_MEMORY_SCOPE_AGENT);
          pf[2 * i + 1] = __hip_atomic_load(s8 + 1, __ATOMIC_RELAXED, __HIP_MEMORY_SCOPE_AGENT);
        }
      }
      const u16* A = &Abuf[c & 1][0];
      // 4-way K-split: wave handles sub-chunks {wave, wave+4} of 8x K=32
#pragma unroll
      for (int si = 0; si < 2; si++) {
        const int s   = wave + si * 4;
        const int kcg = c * 8 + s;                       // global k-chunk 0..39
        const int kl  = s * 32 + ((lane >> 4) << 3);     // elem offset in staged chunk
        short8 bfr0 = *(const short8*)(Bsm + (0 * 40 + kcg) * 512 + lane * 8);
        short8 bfr1 = *(const short8*)(Bsm + (1 * 40 + kcg) * 512 + lane * 8);
#pragma unroll
        for (int mt = 0; mt < 4; mt++) {
          short8 af = *(const short8*)(A + (mt * 16 + (lane & 15)) * 264 + kl);
          acc[mt][0] = __builtin_amdgcn_mfma_f32_16x16x32_bf16(af, bfr0, acc[mt][0], 0, 0, 0);
          acc[mt][1] = __builtin_amdgcn_mfma_f32_16x16x32_bf16(af, bfr1, acc[mt][1], 0, 0, 0);
        }
      }
      if (c < 4) {
#pragma unroll
        for (int i = 0; i < 8; i++) {
          int g = tid + i * 256, row = g >> 5, c8 = g & 31;
          uint4 v;
          v.x = (u32)pf[2 * i];     v.y = (u32)(pf[2 * i] >> 32);
          v.z = (u32)pf[2 * i + 1]; v.w = (u32)(pf[2 * i + 1] >> 32);
          *(uint4*)(&Abuf[(c + 1) & 1][row * 264 + c8 * 8]) = v;
        }
      }
      __syncthreads();
    }

    // K-split reduction: red[wave][col(32)][68 rows-padded]
    {
      const int cb = lane & 15, q = lane >> 4;
#pragma unroll
      for (int mt = 0; mt < 4; mt++)
#pragma unroll
        for (int nt = 0; nt < 2; nt++) {
          int addr = (wave * 32 + nt * 16 + cb) * 68 + mt * 16 + q * 4;
          *(f32x4*)(red + addr) = acc[mt][nt];
        }
    }
    __syncthreads();

    // epilogue: thread owns (b_, hg0, hg1)
    float gv[8];
#pragma unroll
    for (int gg = 0; gg < 4; gg++)
#pragma unroll
      for (int e = 0; e < 2; e++) {
        int col = gg * 8 + hq * 2 + e;
        gv[gg * 2 + e] = red[(0 * 32 + col) * 68 + b_] + red[(1 * 32 + col) * 68 + b_]
                       + red[(2 * 32 + col) * 68 + b_] + red[(3 * 32 + col) * 68 + b_];
      }
    float i0 = sigf(gv[0] + bi0), i1 = sigf(gv[1] + bi1);
    float f0 = sigf(gv[2] + bf0), f1 = sigf(gv[3] + bf1);
    float o0 = sigf(gv[4] + bo0), o1 = sigf(gv[5] + bo1);
    float ct0 = tanhfast(gv[6] + bc0), ct1 = tanhfast(gv[7] + bc1);
    c0v = f0 * c0v + i0 * ct0;  c1v = f1 * c1v + i1 * ct1;
    h0f = o0 * tanhfast(c0v);   h1f = o1 * tanhfast(c1v);

    // pred partial: reduce 4 threads sharing b_, plain store to ws (no atomics)
    float pr = h0f * wd0 + h1f * wd1;
    pr += __shfl_xor(pr, 1);
    pr += __shfl_xor(pr, 2);
    if ((lane & 3) == 0) p.ppart[(size_t)t * NB * 64 + j * 64 + b_] = pr;

    // publish H_t: relaxed agent atomic store -> global_store sc1 (write to LLC)
    u32 hv = (u32)f2bf(h0f) | ((u32)f2bf(h1f) << 16);
    __hip_atomic_store((u32*)(Hw + b_ * HU + hg0), hv,
                       __ATOMIC_RELAXED, __HIP_MEMORY_SCOPE_AGENT);

    // grid barrier, monotonic counter, NO fences. __syncthreads drains vmcnt(0)
    // so every thread's sc1 H-store reached the LLC before tid0's arrival add.
    __syncthreads();
    if (tid == 0) {
      __hip_atomic_fetch_add(p.bar, 1u, __ATOMIC_RELAXED, __HIP_MEMORY_SCOPE_AGENT);
      const u32 tgt = (u32)(NB * (t + 1));
      while (__hip_atomic_load(p.bar, __ATOMIC_RELAXED, __HIP_MEMORY_SCOPE_AGENT) < tgt)
        __builtin_amdgcn_s_sleep(2);
    }
    __syncthreads();
  }

  // finals (plain stores; end-of-kernel release makes them visible to the host)
  p.Hf[b_ * HU + hg0] = h0f; p.Hf[b_ * HU + hg1] = h1f;
  p.Cf[b_ * HU + hg0] = c0v; p.Cf[b_ * HU + hg1] = c1v;
}

// ---------------- launch ----------------

extern "C" void kernel_launch(void* const* d_in, const int* in_sizes, int n_in,
                              void* d_out, int out_size, void* d_ws, size_t ws_size,
                              hipStream_t stream) {
  const float* inputs = (const float*)d_in[0];
  const float* H0  = (const float*)d_in[1];
  const float* C0  = (const float*)d_in[2];
  const float* Wxi = (const float*)d_in[3];
  const float* Whi = (const float*)d_in[4];
  const float* bi  = (const float*)d_in[5];
  const float* Wxf = (const float*)d_in[6];
  const float* Whf = (const float*)d_in[7];
  const float* bf_ = (const float*)d_in[8];
  const float* Wxo = (const float*)d_in[9];
  const float* Who = (const float*)d_in[10];
  const float* bo  = (const float*)d_in[11];
  const float* Wxc = (const float*)d_in[12];
  const float* Whc = (const float*)d_in[13];
  const float* bc  = (const float*)d_in[14];
  const float* Wd  = (const float*)d_in[15];
  const float* bd  = (const float*)d_in[16];

  char* ws = (char*)d_ws;
  u32*   bar   = (u32*)ws;                                     // 128 B
  u16*   Wpack = (u16*)(ws + 128);                             // 10485760 B
  u16*   xbf   = (u16*)(ws + 128 + 10485760);                  // 16777216 B
  u16*   Hbuf  = (u16*)(ws + 128 + 10485760 + 16777216);       // 262144 B
  float* ppart = (float*)(ws + 128 + 10485760 + 16777216 + 262144); // 16777216 B (~44 MB total)

  float* pred = (float*)d_out;
  float* Hf   = pred + BATCH * SEQ;
  float* Cf   = Hf + BATCH * HU;

  k_prep<<<256, 256, 0, stream>>>(H0, Hbuf, bar);
  k_xconv<<<8192, 256, 0, stream>>>(inputs, xbf);
  k_pack<<<2560, 256, 0, stream>>>(Wxi, Whi, Wxf, Whf, Wxo, Who, Wxc, Whc, Wpack);

  MainParams prm{xbf, Wpack, Hbuf, C0, Wd, bi, bf_, bo, bc, ppart, Hf, Cf, bar};
  lstm_main<<<dim3(NB), dim3(256), 0, stream>>>(prm);

  k_predsum<<<128, 256, 0, stream>>>(ppart, bd, pred);
}